// Round 3
// baseline (543.985 us; speedup 1.0000x reference)
//
#include <hip/hip_runtime.h>
#include <hip/hip_bf16.h>
#include <math.h>

// Problem constants (reference: B=64, L=1024, H=64, VOCAB=64)
#define BB 64
#define LL 1024
#define HH 64

typedef float v4f __attribute__((ext_vector_type(4)));
#define FMA4(a, b, c) __builtin_elementwise_fma((a), (b), (c))

// ---------------------------------------------------------------------------
// Kernel 1: per-token phase.
// block = 256 threads (4 waves), 32 tokens/block, grid = 2048.
// All dot products use v4f packed FMA with the SAME partial-sum grouping as
// the scalar version (bit-identical results).
// ---------------------------------------------------------------------------
__global__ __launch_bounds__(256, 1)
void token_kernel(const int* __restrict__ seq,
                  const float* __restrict__ embed_W,
                  const float* __restrict__ ff_W1, const float* __restrict__ ff_b1,
                  const float* __restrict__ ff_W2, const float* __restrict__ ff_b2,
                  const float* __restrict__ ln_g, const float* __restrict__ ln_b,
                  const float* __restrict__ kp_W, const float* __restrict__ vp_W,
                  const float* __restrict__ qp_W,
                  float* __restrict__ knv, float* __restrict__ vthr,
                  float* __restrict__ qbuf)
{
    __shared__ __align__(16) float h_s[32][64];    // 8 KB
    __shared__ __align__(16) float t1_s[32][128];  // 16 KB
    __shared__ __align__(16) float hn_s[32][64];   // 8 KB

    const int tid  = threadIdx.x;
    const int tok0 = blockIdx.x * 32;

    // ---- Stage A: embedding gather into LDS ----
#pragma unroll
    for (int k = 0; k < 8; ++k) {
        int e   = k * 256 + tid;
        int tok = e >> 6, i = e & 63;
        int s   = seq[tok0 + tok];
        h_s[tok][i] = embed_W[s * 64 + i];
    }
    __syncthreads();

    // ---- Stage B: FF1 (64 -> 128, ReLU), packed ----
    {
        const int j = tid & 127;
        const int g = tid >> 7;
        v4f w1v[16];
#pragma unroll
        for (int w = 0; w < 16; ++w) {
            w1v[w].x = ff_W1[(4*w+0) * 128 + j];
            w1v[w].y = ff_W1[(4*w+1) * 128 + j];
            w1v[w].z = ff_W1[(4*w+2) * 128 + j];
            w1v[w].w = ff_W1[(4*w+3) * 128 + j];
        }
        const float b1j = ff_b1[j];
#pragma unroll
        for (int tk = 0; tk < 16; ++tk) {
            const int tok = g * 16 + tk;
            const v4f* h4 = (const v4f*)h_s[tok];
            v4f acc = {b1j, 0.f, 0.f, 0.f};
#pragma unroll
            for (int w = 0; w < 16; ++w) acc = FMA4(h4[w], w1v[w], acc);
            t1_s[tok][j] = fmaxf((acc.x + acc.y) + (acc.z + acc.w), 0.f);
        }
    }
    __syncthreads();

    // ---- Stage C: FF2 (128 -> 64) + residual + LayerNorm, packed ----
    {
        const int i  = tid & 63;
        const int w4 = tid >> 6;
        const float b2i = ff_b2[i];
        const float gi  = ln_g[i];
        const float bi  = ln_b[i];
        float accf[8];
#pragma unroll
        for (int tk = 0; tk < 8; ++tk) accf[tk] = b2i;
#pragma unroll
        for (int h = 0; h < 2; ++h) {
            v4f w2v[16];
#pragma unroll
            for (int w = 0; w < 16; ++w) {
                w2v[w].x = ff_W2[(h*64 + 4*w+0) * 64 + i];
                w2v[w].y = ff_W2[(h*64 + 4*w+1) * 64 + i];
                w2v[w].z = ff_W2[(h*64 + 4*w+2) * 64 + i];
                w2v[w].w = ff_W2[(h*64 + 4*w+3) * 64 + i];
            }
#pragma unroll
            for (int tk = 0; tk < 8; ++tk) {
                const int tok = w4 * 8 + tk;
                const v4f* t4 = (const v4f*)&t1_s[tok][h*64];
                v4f acc = {0.f, 0.f, 0.f, 0.f};
#pragma unroll
                for (int w = 0; w < 16; ++w) acc = FMA4(t4[w], w2v[w], acc);
                accf[tk] += (acc.x + acc.y) + (acc.z + acc.w);
            }
        }
#pragma unroll
        for (int tk = 0; tk < 8; ++tk) {
            const int tok = w4 * 8 + tk;
            float x = h_s[tok][i] + accf[tk];
            float s = x;
#pragma unroll
            for (int m = 32; m > 0; m >>= 1) s += __shfl_xor(s, m);
            float mu = s * (1.f / 64.f);
            float d  = x - mu;
            float s2 = d * d;
#pragma unroll
            for (int m = 32; m > 0; m >>= 1) s2 += __shfl_xor(s2, m);
            float var = s2 * (1.f / 64.f);
            hn_s[tok][i] = d / sqrtf(var + 1e-5f) * gi + bi;
        }
    }
    __syncthreads();

    // ---- Stage D: kn/v packed stream (t<1023) OR q (t==1023) ----
    {
        const int i  = tid & 63;
        const int w4 = tid >> 6;
        v4f kcv[16], vcv[16];
#pragma unroll
        for (int w = 0; w < 16; ++w) {
            kcv[w].x = kp_W[(4*w+0) * 64 + i]; kcv[w].y = kp_W[(4*w+1) * 64 + i];
            kcv[w].z = kp_W[(4*w+2) * 64 + i]; kcv[w].w = kp_W[(4*w+3) * 64 + i];
            vcv[w].x = vp_W[(4*w+0) * 64 + i]; vcv[w].y = vp_W[(4*w+1) * 64 + i];
            vcv[w].z = vp_W[(4*w+2) * 64 + i]; vcv[w].w = vp_W[(4*w+3) * 64 + i];
        }
#pragma unroll
        for (int tk = 0; tk < 8; ++tk) {
            const int tok = w4 * 8 + tk;
            const int tg  = tok0 + tok;
            const int b   = tg >> 10;
            const int t   = tg & 1023;
            const v4f* hn4 = (const v4f*)hn_s[tok];
            if (t < 1023) {
                v4f ka = {0.f,0.f,0.f,0.f}, va = {0.f,0.f,0.f,0.f};
#pragma unroll
                for (int w = 0; w < 16; ++w) {
                    v4f hv = hn4[w];
                    ka = FMA4(hv, kcv[w], ka);
                    va = FMA4(hv, vcv[w], va);
                }
                float kas = (ka.x + ka.y) + (ka.z + ka.w);
                float vas = (va.x + va.y) + (va.z + va.w);
                float kn2 = kas * kas, vn2 = vas * vas;
#pragma unroll
                for (int m = 32; m > 0; m >>= 1) {
                    kn2 += __shfl_xor(kn2, m);
                    vn2 += __shfl_xor(vn2, m);
                }
                float knorm = fmaxf(sqrtf(kn2), 1e-12f);
                size_t row = ((size_t)b * 1024 + t) * 128;
                knv[row + i]      = kas / knorm;
                knv[row + 64 + i] = vas;
                if (i == 0) vthr[b * 1024 + t] = 0.4f * sqrtf(vn2);
            } else {
                v4f qa = {0.f,0.f,0.f,0.f};
#pragma unroll
                for (int w = 0; w < 16; ++w) {
                    v4f qw;
                    qw.x = qp_W[(4*w+0)*64 + i]; qw.y = qp_W[(4*w+1)*64 + i];
                    qw.z = qp_W[(4*w+2)*64 + i]; qw.w = qp_W[(4*w+3)*64 + i];
                    qa = FMA4(hn4[w], qw, qa);
                }
                qbuf[b * 64 + i] = (qa.x + qa.y) + (qa.z + qa.w);
            }
        }
    }
}

// ---------------------------------------------------------------------------
// Kernel 2: sequential fast-weight scan + output head.
// One wave per batch. Lane i owns M row i (16 named v4f = 64 VGPRs).
// TWO full k-register sets (A/B) software-pipeline the LDS->reg stage:
// step t+1's 16 ds_read_b128 are issued before step t's compute, hiding the
// ~120-cycle LDS latency that round 2 exposed 3-4x per step (VGPR=88 -> the
// compiler had no spare regs; now ~215 with __launch_bounds__(64,1)).
// ---------------------------------------------------------------------------

template<int CTRL>
__device__ __forceinline__ float dppadd(float x) {
    int y = __builtin_amdgcn_update_dpp(0, __float_as_int(x), CTRL, 0xF, 0xF, true);
    return x + __int_as_float(y);
}

// load k-set P (16 v4f) + v element + threshold for step S of chunk buffer
#define LDSET(P, BASE, S, TP) do { \
    const v4f* kk_ = (const v4f*)((BASE) + (S) * 128); \
    P##0  = kk_[0];  P##1  = kk_[1];  P##2  = kk_[2];  P##3  = kk_[3]; \
    P##4  = kk_[4];  P##5  = kk_[5];  P##6  = kk_[6];  P##7  = kk_[7]; \
    P##8  = kk_[8];  P##9  = kk_[9];  P##10 = kk_[10]; P##11 = kk_[11]; \
    P##12 = kk_[12]; P##13 = kk_[13]; P##14 = kk_[14]; P##15 = kk_[15]; \
    P##v  = (BASE)[(S) * 128 + 64 + lane]; \
    P##th = (TP)[S]; \
} while (0)

// one scan step on k-set P (dot -> err reduce -> gate -> rank-1 update)
#define CMPSET(P) do { \
    v4f a0_ = FMA4(m0, P##0, FMA4(m4, P##4, FMA4(m8,  P##8,  m12 * P##12))); \
    v4f a1_ = FMA4(m1, P##1, FMA4(m5, P##5, FMA4(m9,  P##9,  m13 * P##13))); \
    v4f a2_ = FMA4(m2, P##2, FMA4(m6, P##6, FMA4(m10, P##10, m14 * P##14))); \
    v4f a3_ = FMA4(m3, P##3, FMA4(m7, P##7, FMA4(m11, P##11, m15 * P##15))); \
    v4f ts_ = (a0_ + a1_) + (a2_ + a3_); \
    float vp_ = (ts_.x + ts_.y) + (ts_.z + ts_.w); \
    float d_ = P##v - vp_; \
    float x_ = d_ * d_; \
    x_ = dppadd<0x111>(x_); x_ = dppadd<0x112>(x_); \
    x_ = dppadd<0x114>(x_); x_ = dppadd<0x118>(x_); \
    x_ = dppadd<0x142>(x_); x_ = dppadd<0x143>(x_); \
    float e_ = __int_as_float(__builtin_amdgcn_readlane(__float_as_int(x_), 63)); \
    float gd_ = (sqrtf(e_) > P##th) ? d_ : 0.0f; \
    v4f gdv_ = {gd_, gd_, gd_, gd_}; \
    m0  = FMA4(gdv_, P##0,  m0);  m1  = FMA4(gdv_, P##1,  m1); \
    m2  = FMA4(gdv_, P##2,  m2);  m3  = FMA4(gdv_, P##3,  m3); \
    m4  = FMA4(gdv_, P##4,  m4);  m5  = FMA4(gdv_, P##5,  m5); \
    m6  = FMA4(gdv_, P##6,  m6);  m7  = FMA4(gdv_, P##7,  m7); \
    m8  = FMA4(gdv_, P##8,  m8);  m9  = FMA4(gdv_, P##9,  m9); \
    m10 = FMA4(gdv_, P##10, m10); m11 = FMA4(gdv_, P##11, m11); \
    m12 = FMA4(gdv_, P##12, m12); m13 = FMA4(gdv_, P##13, m13); \
    m14 = FMA4(gdv_, P##14, m14); m15 = FMA4(gdv_, P##15, m15); \
} while (0)

// pipelined chunk: compute s0..s14, loading s+1 one step ahead (s15 load last)
#define CHUNK_PIPE(bb, tp) \
    LDSET(B, bb, 1,  tp); CMPSET(A); \
    LDSET(A, bb, 2,  tp); CMPSET(B); \
    LDSET(B, bb, 3,  tp); CMPSET(A); \
    LDSET(A, bb, 4,  tp); CMPSET(B); \
    LDSET(B, bb, 5,  tp); CMPSET(A); \
    LDSET(A, bb, 6,  tp); CMPSET(B); \
    LDSET(B, bb, 7,  tp); CMPSET(A); \
    LDSET(A, bb, 8,  tp); CMPSET(B); \
    LDSET(B, bb, 9,  tp); CMPSET(A); \
    LDSET(A, bb, 10, tp); CMPSET(B); \
    LDSET(B, bb, 11, tp); CMPSET(A); \
    LDSET(A, bb, 12, tp); CMPSET(B); \
    LDSET(B, bb, 13, tp); CMPSET(A); \
    LDSET(A, bb, 14, tp); CMPSET(B); \
    LDSET(B, bb, 15, tp); CMPSET(A);

// async copy: 1024 B contiguous global -> contiguous LDS (one inst)
__device__ __forceinline__ void gl2lds_1k(const float* g, float* l, int lane) {
    __builtin_amdgcn_global_load_lds(
        (const __attribute__((address_space(1))) void*)(g + lane * 4),
        (__attribute__((address_space(3))) void*)l, 16, 0, 0);
}

__device__ __forceinline__ void prefetch_chunk(const float* g, float* l, int lane) {
#pragma unroll
    for (int w = 0; w < 8; ++w)
        gl2lds_1k(g + w * 256, l + w * 256, lane);
}

__global__ __launch_bounds__(64, 1)
void scan_kernel(const float* __restrict__ knv,
                 const float* __restrict__ vthr,
                 const float* __restrict__ qbuf,
                 const float* __restrict__ rp_W, const float* __restrict__ rp_b,
                 const float* __restrict__ out_W, const float* __restrict__ out_b,
                 float* __restrict__ out)
{
    const int b    = blockIdx.x;
    const int lane = threadIdx.x;
    const float* knvb = knv  + (size_t)b * 1024 * 128;
    const float* thrb = vthr + (size_t)b * 1024;

    __shared__ __align__(16) float thr_s[1024];     // 4 KB
    __shared__ __align__(16) float buf[2][2048];    // 2 x 8 KB (16 steps each)
    __shared__ float sh[64];

    // M rows + two k-sets as named registers
    v4f m0={0,0,0,0},m1={0,0,0,0},m2={0,0,0,0},m3={0,0,0,0},
        m4={0,0,0,0},m5={0,0,0,0},m6={0,0,0,0},m7={0,0,0,0},
        m8={0,0,0,0},m9={0,0,0,0},m10={0,0,0,0},m11={0,0,0,0},
        m12={0,0,0,0},m13={0,0,0,0},m14={0,0,0,0},m15={0,0,0,0};
    v4f A0,A1,A2,A3,A4,A5,A6,A7,A8,A9,A10,A11,A12,A13,A14,A15;
    v4f B0,B1,B2,B3,B4,B5,B6,B7,B8,B9,B10,B11,B12,B13,B14,B15;
    float Av, Ath, Bv, Bth;

    // prefetch: thr (4 insts), chunk 0 (8), chunk 1 (8) -> 20 outstanding
#pragma unroll
    for (int w = 0; w < 4; ++w) gl2lds_1k(thrb + w * 256, thr_s + w * 256, lane);
    prefetch_chunk(knvb, buf[0], lane);
    prefetch_chunk(knvb + 2048, buf[1], lane);

    asm volatile("s_waitcnt vmcnt(8)" ::: "memory");  // thr + chunk0 landed
    LDSET(A, buf[0], 0, thr_s);

#pragma unroll 1
    for (int c = 0; c < 63; ++c) {
        float* bb = buf[c & 1];
        const float* tp = thr_s + c * 16;
        CHUNK_PIPE(bb, tp)                      // computes s0..s14, B holds s15
        asm volatile("s_waitcnt lgkmcnt(0)" ::: "memory"); // bb reads drained
        if (c < 62) {
            prefetch_chunk(knvb + (size_t)(c + 2) * 2048, bb, lane);
            asm volatile("s_waitcnt vmcnt(8)" ::: "memory"); // chunk c+1 landed
        } else {
            asm volatile("s_waitcnt vmcnt(0)" ::: "memory"); // chunk 63 landed
        }
        LDSET(A, buf[(c + 1) & 1], 0, thr_s + (c + 1) * 16);
        CMPSET(B);                              // s15 of chunk c
    }

    {   // tail chunk 63: steps t = 1008..1022 (s0..s14), A holds s0
        float* bb = buf[1];
        const float* tp = thr_s + 63 * 16;
        LDSET(B, bb, 1,  tp); CMPSET(A);
        LDSET(A, bb, 2,  tp); CMPSET(B);
        LDSET(B, bb, 3,  tp); CMPSET(A);
        LDSET(A, bb, 4,  tp); CMPSET(B);
        LDSET(B, bb, 5,  tp); CMPSET(A);
        LDSET(A, bb, 6,  tp); CMPSET(B);
        LDSET(B, bb, 7,  tp); CMPSET(A);
        LDSET(A, bb, 8,  tp); CMPSET(B);
        LDSET(B, bb, 9,  tp); CMPSET(A);
        LDSET(A, bb, 10, tp); CMPSET(B);
        LDSET(B, bb, 11, tp); CMPSET(A);
        LDSET(A, bb, 12, tp); CMPSET(B);
        LDSET(B, bb, 13, tp); CMPSET(A);
        LDSET(A, bb, 14, tp); CMPSET(B);
        CMPSET(A);                              // t = 1022
    }

    // ---- output head: vq = M q ; r = vq @ rp_W + rp_b ; out = r @ out_W + out_b
    const v4f* qq = (const v4f*)(qbuf + b * 64);
    v4f accq = {0.f, 0.f, 0.f, 0.f};
    accq = FMA4(m0,  qq[0],  accq); accq = FMA4(m1,  qq[1],  accq);
    accq = FMA4(m2,  qq[2],  accq); accq = FMA4(m3,  qq[3],  accq);
    accq = FMA4(m4,  qq[4],  accq); accq = FMA4(m5,  qq[5],  accq);
    accq = FMA4(m6,  qq[6],  accq); accq = FMA4(m7,  qq[7],  accq);
    accq = FMA4(m8,  qq[8],  accq); accq = FMA4(m9,  qq[9],  accq);
    accq = FMA4(m10, qq[10], accq); accq = FMA4(m11, qq[11], accq);
    accq = FMA4(m12, qq[12], accq); accq = FMA4(m13, qq[13], accq);
    accq = FMA4(m14, qq[14], accq); accq = FMA4(m15, qq[15], accq);
    float vq = (accq.x + accq.y) + (accq.z + accq.w);

    sh[lane] = vq;
    __syncthreads();
    float r = rp_b[lane];
#pragma unroll
    for (int ii = 0; ii < 64; ++ii) r = fmaf(sh[ii], rp_W[ii * 64 + lane], r);
    __syncthreads();
    sh[lane] = r;
    __syncthreads();
    float o = out_b[lane];
#pragma unroll
    for (int ii = 0; ii < 64; ++ii) o = fmaf(sh[ii], out_W[ii * 64 + lane], o);
    out[b * 64 + lane] = o;
}

// ---------------------------------------------------------------------------
// Launch. Workspace (fp32): knv[64][1024][128] (33.55 MB, t=1023 row unused) |
// vthr[64][1024] (262 KB) | qbuf[64][64]. Total ~33.9 MB.
// ---------------------------------------------------------------------------
extern "C" void kernel_launch(void* const* d_in, const int* in_sizes, int n_in,
                              void* d_out, int out_size, void* d_ws, size_t ws_size,
                              hipStream_t stream)
{
    const int*   seq   = (const int*)  d_in[0];
    const float* embed = (const float*)d_in[1];
    const float* ffW1  = (const float*)d_in[2];
    const float* ffb1  = (const float*)d_in[3];
    const float* ffW2  = (const float*)d_in[4];
    const float* ffb2  = (const float*)d_in[5];
    const float* lng   = (const float*)d_in[6];
    const float* lnb   = (const float*)d_in[7];
    const float* kpW   = (const float*)d_in[8];
    const float* vpW   = (const float*)d_in[9];
    const float* qpW   = (const float*)d_in[10];
    const float* rpW   = (const float*)d_in[11];
    const float* rpb   = (const float*)d_in[12];
    const float* outW  = (const float*)d_in[13];
    const float* outb  = (const float*)d_in[14];
    float* out = (float*)d_out;

    float* knv  = (float*)d_ws;
    float* vthr = knv  + (size_t)64 * 1024 * 128;
    float* qbuf = vthr + (size_t)64 * 1024;

    token_kernel<<<2048, 256, 0, stream>>>(seq, embed, ffW1, ffb1, ffW2, ffb2,
                                           lng, lnb, kpW, vpW, qpW,
                                           knv, vthr, qbuf);
    scan_kernel<<<64, 64, 0, stream>>>(knv, vthr, qbuf,
                                       rpW, rpb, outW, outb, out);
}

// Round 6
// 521.910 us; speedup vs baseline: 1.0423x; 1.0423x over previous
//
#include <hip/hip_runtime.h>
#include <hip/hip_bf16.h>
#include <math.h>

// Problem constants (reference: B=64, L=1024, H=64, VOCAB=64)
#define BB 64
#define LL 1024
#define HH 64

typedef float v4f __attribute__((ext_vector_type(4)));
#define FMA4(a, b, c) __builtin_elementwise_fma((a), (b), (c))

// ---------------------------------------------------------------------------
// Kernel 1: per-token phase.
// block = 256 threads (4 waves), 32 tokens/block, grid = 2048.
// Writes packed stream knv[b][t] = [kn(64) | v(64)] and vthr[b][t] =
// 0.4*sqrt(vn2)  (EXACT R2/R3 gate numerics; gate chain is bit-path-sensitive).
// ---------------------------------------------------------------------------
__global__ __launch_bounds__(256, 1)
void token_kernel(const int* __restrict__ seq,
                  const float* __restrict__ embed_W,
                  const float* __restrict__ ff_W1, const float* __restrict__ ff_b1,
                  const float* __restrict__ ff_W2, const float* __restrict__ ff_b2,
                  const float* __restrict__ ln_g, const float* __restrict__ ln_b,
                  const float* __restrict__ kp_W, const float* __restrict__ vp_W,
                  const float* __restrict__ qp_W,
                  float* __restrict__ knv, float* __restrict__ vthr,
                  float* __restrict__ qbuf)
{
    __shared__ __align__(16) float h_s[32][64];    // 8 KB
    __shared__ __align__(16) float t1_s[32][128];  // 16 KB
    __shared__ __align__(16) float hn_s[32][64];   // 8 KB

    const int tid  = threadIdx.x;
    const int tok0 = blockIdx.x * 32;

    // ---- Stage A: embedding gather into LDS ----
#pragma unroll
    for (int k = 0; k < 8; ++k) {
        int e   = k * 256 + tid;
        int tok = e >> 6, i = e & 63;
        int s   = seq[tok0 + tok];
        h_s[tok][i] = embed_W[s * 64 + i];
    }
    __syncthreads();

    // ---- Stage B: FF1 (64 -> 128, ReLU), packed ----
    {
        const int j = tid & 127;
        const int g = tid >> 7;
        v4f w1v[16];
#pragma unroll
        for (int w = 0; w < 16; ++w) {
            w1v[w].x = ff_W1[(4*w+0) * 128 + j];
            w1v[w].y = ff_W1[(4*w+1) * 128 + j];
            w1v[w].z = ff_W1[(4*w+2) * 128 + j];
            w1v[w].w = ff_W1[(4*w+3) * 128 + j];
        }
        const float b1j = ff_b1[j];
#pragma unroll
        for (int tk = 0; tk < 16; ++tk) {
            const int tok = g * 16 + tk;
            const v4f* h4 = (const v4f*)h_s[tok];
            v4f acc = {b1j, 0.f, 0.f, 0.f};
#pragma unroll
            for (int w = 0; w < 16; ++w) acc = FMA4(h4[w], w1v[w], acc);
            t1_s[tok][j] = fmaxf((acc.x + acc.y) + (acc.z + acc.w), 0.f);
        }
    }
    __syncthreads();

    // ---- Stage C: FF2 (128 -> 64) + residual + LayerNorm, packed ----
    {
        const int i  = tid & 63;
        const int w4 = tid >> 6;
        const float b2i = ff_b2[i];
        const float gi  = ln_g[i];
        const float bi  = ln_b[i];
        float accf[8];
#pragma unroll
        for (int tk = 0; tk < 8; ++tk) accf[tk] = b2i;
#pragma unroll
        for (int h = 0; h < 2; ++h) {
            v4f w2v[16];
#pragma unroll
            for (int w = 0; w < 16; ++w) {
                w2v[w].x = ff_W2[(h*64 + 4*w+0) * 64 + i];
                w2v[w].y = ff_W2[(h*64 + 4*w+1) * 64 + i];
                w2v[w].z = ff_W2[(h*64 + 4*w+2) * 64 + i];
                w2v[w].w = ff_W2[(h*64 + 4*w+3) * 64 + i];
            }
#pragma unroll
            for (int tk = 0; tk < 8; ++tk) {
                const int tok = w4 * 8 + tk;
                const v4f* t4 = (const v4f*)&t1_s[tok][h*64];
                v4f acc = {0.f, 0.f, 0.f, 0.f};
#pragma unroll
                for (int w = 0; w < 16; ++w) acc = FMA4(t4[w], w2v[w], acc);
                accf[tk] += (acc.x + acc.y) + (acc.z + acc.w);
            }
        }
#pragma unroll
        for (int tk = 0; tk < 8; ++tk) {
            const int tok = w4 * 8 + tk;
            float x = h_s[tok][i] + accf[tk];
            float s = x;
#pragma unroll
            for (int m = 32; m > 0; m >>= 1) s += __shfl_xor(s, m);
            float mu = s * (1.f / 64.f);
            float d  = x - mu;
            float s2 = d * d;
#pragma unroll
            for (int m = 32; m > 0; m >>= 1) s2 += __shfl_xor(s2, m);
            float var = s2 * (1.f / 64.f);
            hn_s[tok][i] = d / sqrtf(var + 1e-5f) * gi + bi;
        }
    }
    __syncthreads();

    // ---- Stage D: kn/v packed stream (t<1023) OR q (t==1023) ----
    {
        const int i  = tid & 63;
        const int w4 = tid >> 6;
        v4f kcv[16], vcv[16];
#pragma unroll
        for (int w = 0; w < 16; ++w) {
            kcv[w].x = kp_W[(4*w+0) * 64 + i]; kcv[w].y = kp_W[(4*w+1) * 64 + i];
            kcv[w].z = kp_W[(4*w+2) * 64 + i]; kcv[w].w = kp_W[(4*w+3) * 64 + i];
            vcv[w].x = vp_W[(4*w+0) * 64 + i]; vcv[w].y = vp_W[(4*w+1) * 64 + i];
            vcv[w].z = vp_W[(4*w+2) * 64 + i]; vcv[w].w = vp_W[(4*w+3) * 64 + i];
        }
#pragma unroll
        for (int tk = 0; tk < 8; ++tk) {
            const int tok = w4 * 8 + tk;
            const int tg  = tok0 + tok;
            const int b   = tg >> 10;
            const int t   = tg & 1023;
            const v4f* hn4 = (const v4f*)hn_s[tok];
            if (t < 1023) {
                v4f ka = {0.f,0.f,0.f,0.f}, va = {0.f,0.f,0.f,0.f};
#pragma unroll
                for (int w = 0; w < 16; ++w) {
                    v4f hv = hn4[w];
                    ka = FMA4(hv, kcv[w], ka);
                    va = FMA4(hv, vcv[w], va);
                }
                float kas = (ka.x + ka.y) + (ka.z + ka.w);
                float vas = (va.x + va.y) + (va.z + va.w);
                float kn2 = kas * kas, vn2 = vas * vas;
#pragma unroll
                for (int m = 32; m > 0; m >>= 1) {
                    kn2 += __shfl_xor(kn2, m);
                    vn2 += __shfl_xor(vn2, m);
                }
                float knorm = fmaxf(sqrtf(kn2), 1e-12f);
                size_t row = ((size_t)b * 1024 + t) * 128;
                knv[row + i]      = kas / knorm;
                knv[row + 64 + i] = vas;
                if (i == 0) vthr[b * 1024 + t] = 0.4f * sqrtf(vn2);
            } else {
                v4f qa = {0.f,0.f,0.f,0.f};
#pragma unroll
                for (int w = 0; w < 16; ++w) {
                    v4f qw;
                    qw.x = qp_W[(4*w+0)*64 + i]; qw.y = qp_W[(4*w+1)*64 + i];
                    qw.z = qp_W[(4*w+2)*64 + i]; qw.w = qp_W[(4*w+3)*64 + i];
                    qa = FMA4(hn4[w], qw, qa);
                }
                qbuf[b * 64 + i] = (qa.x + qa.y) + (qa.z + qa.w);
            }
        }
    }
}

// ---------------------------------------------------------------------------
// Kernel 2: sequential fast-weight scan + output head.
// One wave per batch (64 blocks x 64 threads). Lane i owns M row i (16 v4f).
// 56-step LDS chunks (28 KB), double-buffered via global_load_lds; ONE
// vmcnt(0) per chunk. Depth-2 A/B register pipeline in a rolled loop.
// R4/R5 BUG FIXED HERE: prefetch guard was `c < 16`, so chunk 18 (the
// 15-step tail) was never DMA'd -- tail ran on chunk-16 stale data
// (deterministic absmax 3.25 in both rounds). Guard is now `c < 17`.
// ---------------------------------------------------------------------------

template<int CTRL>
__device__ __forceinline__ float dppadd(float x) {
    int y = __builtin_amdgcn_update_dpp(0, __float_as_int(x), CTRL, 0xF, 0xF, true);
    return x + __int_as_float(y);
}

// load k-set P (16 v4f) + v element + threshold for step S
#define LDSET(P, BASE, S, TP) do { \
    const v4f* kk_ = (const v4f*)((BASE) + (S) * 128); \
    P##0  = kk_[0];  P##1  = kk_[1];  P##2  = kk_[2];  P##3  = kk_[3]; \
    P##4  = kk_[4];  P##5  = kk_[5];  P##6  = kk_[6];  P##7  = kk_[7]; \
    P##8  = kk_[8];  P##9  = kk_[9];  P##10 = kk_[10]; P##11 = kk_[11]; \
    P##12 = kk_[12]; P##13 = kk_[13]; P##14 = kk_[14]; P##15 = kk_[15]; \
    P##v  = (BASE)[(S) * 128 + 64 + lane]; \
    P##th = (TP)[S]; \
} while (0)

// one scan step on k-set P (dot -> err reduce -> gate -> rank-1 update)
// Bit-identical to the R2/R3 step (sqrtf compare).
#define CMPSET(P) do { \
    v4f a0_ = FMA4(m0, P##0, FMA4(m4, P##4, FMA4(m8,  P##8,  m12 * P##12))); \
    v4f a1_ = FMA4(m1, P##1, FMA4(m5, P##5, FMA4(m9,  P##9,  m13 * P##13))); \
    v4f a2_ = FMA4(m2, P##2, FMA4(m6, P##6, FMA4(m10, P##10, m14 * P##14))); \
    v4f a3_ = FMA4(m3, P##3, FMA4(m7, P##7, FMA4(m11, P##11, m15 * P##15))); \
    v4f ts_ = (a0_ + a1_) + (a2_ + a3_); \
    float vp_ = (ts_.x + ts_.y) + (ts_.z + ts_.w); \
    float d_ = P##v - vp_; \
    float x_ = d_ * d_; \
    x_ = dppadd<0x111>(x_); x_ = dppadd<0x112>(x_); \
    x_ = dppadd<0x114>(x_); x_ = dppadd<0x118>(x_); \
    x_ = dppadd<0x142>(x_); x_ = dppadd<0x143>(x_); \
    float e_ = __int_as_float(__builtin_amdgcn_readlane(__float_as_int(x_), 63)); \
    float gd_ = (sqrtf(e_) > P##th) ? d_ : 0.0f; \
    v4f gdv_ = {gd_, gd_, gd_, gd_}; \
    m0  = FMA4(gdv_, P##0,  m0);  m1  = FMA4(gdv_, P##1,  m1); \
    m2  = FMA4(gdv_, P##2,  m2);  m3  = FMA4(gdv_, P##3,  m3); \
    m4  = FMA4(gdv_, P##4,  m4);  m5  = FMA4(gdv_, P##5,  m5); \
    m6  = FMA4(gdv_, P##6,  m6);  m7  = FMA4(gdv_, P##7,  m7); \
    m8  = FMA4(gdv_, P##8,  m8);  m9  = FMA4(gdv_, P##9,  m9); \
    m10 = FMA4(gdv_, P##10, m10); m11 = FMA4(gdv_, P##11, m11); \
    m12 = FMA4(gdv_, P##12, m12); m13 = FMA4(gdv_, P##13, m13); \
    m14 = FMA4(gdv_, P##14, m14); m15 = FMA4(gdv_, P##15, m15); \
} while (0)

// async copy: 1024 B contiguous global -> contiguous LDS (one inst)
__device__ __forceinline__ void gl2lds_1k(const float* g, float* l, int lane) {
    __builtin_amdgcn_global_load_lds(
        (const __attribute__((address_space(1))) void*)(g + lane * 4),
        (__attribute__((address_space(3))) void*)l, 16, 0, 0);
}

#define SPC   56            // steps per chunk
#define CPF   (SPC * 128)   // floats per chunk (7168)

__device__ __forceinline__ void prefetch_chunk(const float* g, float* l, int lane) {
#pragma unroll
    for (int w = 0; w < 28; ++w)        // 28 x 1 KB = 28 KB
        gl2lds_1k(g + w * 256, l + w * 256, lane);
}

__global__ __launch_bounds__(64, 1)
void scan_kernel(const float* __restrict__ knv,
                 const float* __restrict__ vthr,
                 const float* __restrict__ qbuf,
                 const float* __restrict__ rp_W, const float* __restrict__ rp_b,
                 const float* __restrict__ out_W, const float* __restrict__ out_b,
                 float* __restrict__ out)
{
    const int b    = blockIdx.x;
    const int lane = threadIdx.x;
    const float* knvb = knv  + (size_t)b * 1024 * 128;
    const float* thrb = vthr + (size_t)b * 1024;

    __shared__ __align__(16) float thr_s[1024];     // 4 KB
    __shared__ __align__(16) float buf[2][CPF];     // 2 x 28 KB
    __shared__ float sh[64];

    v4f m0={0,0,0,0},m1={0,0,0,0},m2={0,0,0,0},m3={0,0,0,0},
        m4={0,0,0,0},m5={0,0,0,0},m6={0,0,0,0},m7={0,0,0,0},
        m8={0,0,0,0},m9={0,0,0,0},m10={0,0,0,0},m11={0,0,0,0},
        m12={0,0,0,0},m13={0,0,0,0},m14={0,0,0,0},m15={0,0,0,0};
    v4f A0,A1,A2,A3,A4,A5,A6,A7,A8,A9,A10,A11,A12,A13,A14,A15;
    v4f B0,B1,B2,B3,B4,B5,B6,B7,B8,B9,B10,B11,B12,B13,B14,B15;
    float Av, Ath, Bv, Bth;

    // thr (4 KB) + chunk 0
#pragma unroll
    for (int w = 0; w < 4; ++w) gl2lds_1k(thrb + w * 256, thr_s + w * 256, lane);
    prefetch_chunk(knvb, buf[0], lane);
    asm volatile("s_waitcnt vmcnt(0)" ::: "memory");
    prefetch_chunk(knvb + CPF, buf[1], lane);       // chunk 1 in flight

    // 18 full chunks (1008 steps) + 15-step tail = 1023
#pragma unroll 1
    for (int c = 0; c < 18; ++c) {
        const float* bb = buf[c & 1];
        const float* tp = thr_s + c * SPC;
        LDSET(A, bb, 0, tp);
        LDSET(B, bb, 1, tp);
#pragma unroll 1
        for (int i = 0; i < 27; ++i) {
            const int s = 2 * i;
            CMPSET(A); LDSET(A, bb, s + 2, tp);
            CMPSET(B); LDSET(B, bb, s + 3, tp);
        }
        CMPSET(A);   // step 54
        CMPSET(B);   // step 55
        asm volatile("s_waitcnt vmcnt(0)" ::: "memory");   // next chunk landed
        if (c < 17)   // c=16 prefetches chunk 18 (tail) into buf[0]  [R4/R5 fix]
            prefetch_chunk(knvb + (size_t)(c + 2) * CPF, (float*)buf[c & 1], lane);
    }

    {   // tail: steps 1008..1022 (15 steps) from buf[0] (= chunk 18)
        const float* bb = buf[0];
        const float* tp = thr_s + 18 * SPC;
        LDSET(A, bb, 0, tp);
        LDSET(B, bb, 1, tp);
#pragma unroll 1
        for (int i = 0; i < 6; ++i) {
            const int s = 2 * i;
            CMPSET(A); LDSET(A, bb, s + 2, tp);
            CMPSET(B); LDSET(B, bb, s + 3, tp);
        }
        CMPSET(A); LDSET(A, bb, 14, tp);   // step 12
        CMPSET(B);                          // step 13
        CMPSET(A);                          // step 14 -> t = 1022
    }

    // ---- output head: vq = M q ; r = vq @ rp_W + rp_b ; out = r @ out_W + out_b
    const v4f* qq = (const v4f*)(qbuf + b * 64);
    v4f accq = {0.f, 0.f, 0.f, 0.f};
    accq = FMA4(m0,  qq[0],  accq); accq = FMA4(m1,  qq[1],  accq);
    accq = FMA4(m2,  qq[2],  accq); accq = FMA4(m3,  qq[3],  accq);
    accq = FMA4(m4,  qq[4],  accq); accq = FMA4(m5,  qq[5],  accq);
    accq = FMA4(m6,  qq[6],  accq); accq = FMA4(m7,  qq[7],  accq);
    accq = FMA4(m8,  qq[8],  accq); accq = FMA4(m9,  qq[9],  accq);
    accq = FMA4(m10, qq[10], accq); accq = FMA4(m11, qq[11], accq);
    accq = FMA4(m12, qq[12], accq); accq = FMA4(m13, qq[13], accq);
    accq = FMA4(m14, qq[14], accq); accq = FMA4(m15, qq[15], accq);
    float vq = (accq.x + accq.y) + (accq.z + accq.w);

    sh[lane] = vq;
    __syncthreads();
    float r = rp_b[lane];
#pragma unroll
    for (int ii = 0; ii < 64; ++ii) r = fmaf(sh[ii], rp_W[ii * 64 + lane], r);
    __syncthreads();
    sh[lane] = r;
    __syncthreads();
    float o = out_b[lane];
#pragma unroll
    for (int ii = 0; ii < 64; ++ii) o = fmaf(sh[ii], out_W[ii * 64 + lane], o);
    out[b * 64 + lane] = o;
}

// ---------------------------------------------------------------------------
// Launch. Workspace (fp32): knv[64][1024][128] (33.55 MB, t=1023 row unused;
// chunk-18 DMA overreads ~20 KB past batch 63's rows into vthr -- in-bounds,
// unused) | vthr[64][1024] (262 KB) | qbuf[64][64]. Total ~33.9 MB.
// ---------------------------------------------------------------------------
extern "C" void kernel_launch(void* const* d_in, const int* in_sizes, int n_in,
                              void* d_out, int out_size, void* d_ws, size_t ws_size,
                              hipStream_t stream)
{
    const int*   seq   = (const int*)  d_in[0];
    const float* embed = (const float*)d_in[1];
    const float* ffW1  = (const float*)d_in[2];
    const float* ffb1  = (const float*)d_in[3];
    const float* ffW2  = (const float*)d_in[4];
    const float* ffb2  = (const float*)d_in[5];
    const float* lng   = (const float*)d_in[6];
    const float* lnb   = (const float*)d_in[7];
    const float* kpW   = (const float*)d_in[8];
    const float* vpW   = (const float*)d_in[9];
    const float* qpW   = (const float*)d_in[10];
    const float* rpW   = (const float*)d_in[11];
    const float* rpb   = (const float*)d_in[12];
    const float* outW  = (const float*)d_in[13];
    const float* outb  = (const float*)d_in[14];
    float* out = (float*)d_out;

    float* knv  = (float*)d_ws;
    float* vthr = knv  + (size_t)64 * 1024 * 128;
    float* qbuf = vthr + (size_t)64 * 1024;

    token_kernel<<<2048, 256, 0, stream>>>(seq, embed, ffW1, ffb1, ffW2, ffb2,
                                           lng, lnb, kpW, vpW, qpW,
                                           knv, vthr, qbuf);
    scan_kernel<<<64, 64, 0, stream>>>(knv, vthr, qbuf,
                                       rpW, rpb, outW, outb, out);
}